// Round 1
// baseline (3717.867 us; speedup 1.0000x reference)
//
#include <hip/hip_runtime.h>
#include <stdint.h>

typedef __attribute__((ext_vector_type(8))) short short8;
typedef __attribute__((ext_vector_type(4))) float floatx4;
typedef unsigned short ushort_t;

#define HDIM 128
#define K1   384
#define BM   256
#define BK   32

__device__ __forceinline__ unsigned pack_bf16x2(float a, float b) {
  unsigned ua = __float_as_uint(a), ub = __float_as_uint(b);
  ua += 0x7FFFu + ((ua >> 16) & 1u);   // RNE
  ub += 0x7FFFu + ((ub >> 16) & 1u);
  return (ua >> 16) | (ub & 0xFFFF0000u);
}

__device__ __forceinline__ unsigned short bf16_rne(float f) {
  unsigned u = __float_as_uint(f);
  u += 0x7FFFu + ((u >> 16) & 1u);
  return (unsigned short)(u >> 16);
}

// Convert x -> bf16 copy, and W1/W2 (K-major) -> transposed bf16 Bt[n][k] for 3 MLPs.
__global__ void prep_kernel(const float* __restrict__ x,
    const float* __restrict__ w1a, const float* __restrict__ w2a,
    const float* __restrict__ w1b, const float* __restrict__ w2b,
    const float* __restrict__ w1c, const float* __restrict__ w2c,
    unsigned short* __restrict__ xb, unsigned short* __restrict__ bts, int Nx)
{
  int tid = blockIdx.x * 256 + threadIdx.x;
  if (tid < Nx) {                      // x: pack 2 floats -> 2 bf16
    float2 v = ((const float2*)x)[tid];
    ((unsigned*)xb)[tid] = pack_bf16x2(v.x, v.y);
    return;
  }
  int wI = tid - Nx;
  if (wI >= 3 * 65536) return;
  int m = wI >> 16;
  int r = wI & 65535;
  const float* W1 = (m == 0) ? w1a : (m == 1) ? w1b : w1c;
  const float* W2 = (m == 0) ? w2a : (m == 1) ? w2b : w2c;
  unsigned short* base = bts + (size_t)m * 65536;
  if (r < 49152) {                     // Bt1[n*384+k] = W1[k*128+n]
    int n = r / 384, k = r % 384;
    base[r] = bf16_rne(W1[(size_t)k * 128 + n]);
  } else {                             // Bt2[n*128+k] = W2[k*128+n]
    int r2 = r - 49152;
    int n = r2 >> 7, k = r2 & 127;
    base[49152 + r2] = bf16_rne(W2[(size_t)k * 128 + n]);
  }
}

// MODE 0: edge block (gather via sidx/ridx, scatter-add into aggp)
// MODE 1: node block (identity rows; seg1f/seg2f are agg_m/agg_w fp32)
template <int MODE>
__global__ __launch_bounds__(256, 2) void mlp_ln_kernel(
    const unsigned short* __restrict__ xb,
    const float* __restrict__ seg1f,
    const float* __restrict__ seg2f,
    const float* __restrict__ residf,
    const int* __restrict__ sidx, const int* __restrict__ ridx,
    const unsigned short* __restrict__ Bt1, const unsigned short* __restrict__ Bt2,
    const float* __restrict__ b1p, const float* __restrict__ b2p,
    const float* __restrict__ gp, const float* __restrict__ betap,
    float* __restrict__ outp, float* __restrict__ aggp,
    int E)
{
  // LDS: bufB (128 x 40 bf16) + union{ bufA 256 x 40 | bufH 128 x 136 } = 45 KB
  __shared__ unsigned short bufB[128 * 40];
  __shared__ unsigned short bufU[128 * 136];
  unsigned short* bufA = bufU;
  unsigned short* bufH = bufU;

  const int t = threadIdx.x;
  const int lane = t & 63, w = t >> 6;
  const int c = lane & 15, q = lane >> 4;
  const long long e0 = (long long)blockIdx.x * BM;

  // per-thread A-staging row (bf16 gather path: one row per thread)
  long long eg_t = e0 + t;
  if (eg_t > E - 1) eg_t = E - 1;
  const int rowc = (int)eg_t;
  int sIdx = 0, rIdx = 0;
  if (MODE == 0) { sIdx = sidx[rowc]; rIdx = ridx[rowc]; }

  int4 pa[8];
  int4 pb[2];

  auto loadB = [&](const unsigned short* Bt, int Kb, int kk) {
    int n = t >> 1;
#pragma unroll
    for (int i = 0; i < 2; ++i) {
      int sub = 2 * (t & 1) + i;
      pb[i] = *(const int4*)(Bt + (size_t)n * Kb + kk + sub * 8);
    }
  };
  auto storeB = [&]() {
    int n = t >> 1;
#pragma unroll
    for (int i = 0; i < 2; ++i) {
      int sub = 2 * (t & 1) + i;
      *(int4*)&bufB[n * 40 + sub * 8] = pb[i];
    }
  };
  auto loadA = [&](int kt) {
    int kk = kt * BK;
    int seg = kk >> 7;
    int ko = kk & 127;
    bool bfseg = (seg == 0) || (MODE == 0 && seg == 1);
    if (bfseg) {
      const unsigned short* src;
      if (seg == 0) src = xb + (size_t)((MODE == 0) ? sIdx : rowc) * HDIM + ko;
      else          src = xb + (size_t)rIdx * HDIM + ko;
      const int4* s4 = (const int4*)src;
      pa[0] = s4[0]; pa[1] = s4[1]; pa[2] = s4[2]; pa[3] = s4[3];
    } else {
      const float* base = (MODE == 0) ? seg2f : ((seg == 1) ? seg1f : seg2f);
#pragma unroll
      for (int j = 0; j < 4; ++j) {
        int P = j * 256 + t;
        int row = P >> 2, sub = P & 3;
        long long gr = e0 + row; if (gr > E - 1) gr = E - 1;
        const int4* s4 = (const int4*)(base + (size_t)gr * HDIM + ko + sub * 8);
        pa[2 * j]     = s4[0];
        pa[2 * j + 1] = s4[1];
      }
    }
  };
  auto storeA = [&](int kt) {
    int kk = kt * BK;
    int seg = kk >> 7;
    bool bfseg = (seg == 0) || (MODE == 0 && seg == 1);
    if (bfseg) {
      int4* d = (int4*)&bufA[t * 40];
      d[0] = pa[0]; d[1] = pa[1]; d[2] = pa[2]; d[3] = pa[3];
    } else {
#pragma unroll
      for (int j = 0; j < 4; ++j) {
        int P = j * 256 + t;
        int row = P >> 2, sub = P & 3;
        int4 a0 = pa[2 * j], a1 = pa[2 * j + 1];
        int4 wv;
        wv.x = pack_bf16x2(__int_as_float(a0.x), __int_as_float(a0.y));
        wv.y = pack_bf16x2(__int_as_float(a0.z), __int_as_float(a0.w));
        wv.z = pack_bf16x2(__int_as_float(a1.x), __int_as_float(a1.y));
        wv.w = pack_bf16x2(__int_as_float(a1.z), __int_as_float(a1.w));
        *(int4*)&bufA[row * 40 + sub * 8] = wv;
      }
    }
  };

  // ---------------- GEMM1: [256 x 384] @ [384 x 128] ----------------
  floatx4 acc1[4][8];
#pragma unroll
  for (int mi = 0; mi < 4; ++mi)
#pragma unroll
    for (int nt = 0; nt < 8; ++nt) acc1[mi][nt] = (floatx4){0.f, 0.f, 0.f, 0.f};

  loadA(0); loadB(Bt1, K1, 0);
  for (int kt = 0; kt < 12; ++kt) {
    __syncthreads();
    storeA(kt); storeB();
    if (kt < 11) { loadA(kt + 1); loadB(Bt1, K1, (kt + 1) * BK); }
    else         { loadB(Bt2, 128, 0); }        // prefetch first GEMM2 B slice
    __syncthreads();
    short8 af[4];
#pragma unroll
    for (int mi = 0; mi < 4; ++mi)
      af[mi] = *(const short8*)&bufA[(w * 64 + mi * 16 + c) * 40 + q * 8];
#pragma unroll
    for (int nt = 0; nt < 8; ++nt) {
      short8 bf = *(const short8*)&bufB[(nt * 16 + c) * 40 + q * 8];
#pragma unroll
      for (int mi = 0; mi < 4; ++mi)
        acc1[mi][nt] = __builtin_amdgcn_mfma_f32_16x16x32_bf16(af[mi], bf, acc1[mi][nt], 0, 0, 0);
    }
  }

  // ---------------- GEMM2 + LN, two row-halves ----------------
  for (int h = 0; h < 2; ++h) {
    floatx4 acc2[2][8];
#pragma unroll
    for (int mip = 0; mip < 2; ++mip)
#pragma unroll
      for (int nt = 0; nt < 8; ++nt) acc2[mip][nt] = (floatx4){0.f, 0.f, 0.f, 0.f};

    for (int kt2 = 0; kt2 < 4; ++kt2) {
      __syncthreads();
      if (kt2 == 0) {
        // bias + ReLU + bf16, write h1 half into bufH (own-wave rows only)
        float b1v[8];
#pragma unroll
        for (int nt = 0; nt < 8; ++nt) b1v[nt] = b1p[nt * 16 + c];
#pragma unroll
        for (int mip = 0; mip < 2; ++mip) {
          int mi = 2 * h + mip;
#pragma unroll
          for (int nt = 0; nt < 8; ++nt) {
#pragma unroll
            for (int r = 0; r < 4; ++r) {
              float v = acc1[mi][nt][r] + b1v[nt];
              v = fmaxf(v, 0.0f);
              bufH[(w * 32 + mip * 16 + q * 4 + r) * 136 + nt * 16 + c] = bf16_rne(v);
            }
          }
        }
      }
      storeB();
      int u = h * 4 + kt2;
      if (u < 7) loadB(Bt2, 128, ((u + 1) & 3) * BK);
      __syncthreads();
      short8 af2[2];
#pragma unroll
      for (int mip = 0; mip < 2; ++mip)
        af2[mip] = *(const short8*)&bufH[(w * 32 + mip * 16 + c) * 136 + kt2 * 32 + q * 8];
#pragma unroll
      for (int nt = 0; nt < 8; ++nt) {
        short8 bf = *(const short8*)&bufB[(nt * 16 + c) * 40 + q * 8];
#pragma unroll
        for (int mip = 0; mip < 2; ++mip)
          acc2[mip][nt] = __builtin_amdgcn_mfma_f32_16x16x32_bf16(af2[mip], bf, acc2[mip][nt], 0, 0, 0);
      }
    }

    // epilogue: bias2 + LayerNorm + residual store + scatter
    float b2v[8], gv[8], bev[8];
#pragma unroll
    for (int nt = 0; nt < 8; ++nt) {
      b2v[nt] = b2p[nt * 16 + c];
      gv[nt]  = gp[nt * 16 + c];
      bev[nt] = betap[nt * 16 + c];
    }
#pragma unroll
    for (int mip = 0; mip < 2; ++mip) {
#pragma unroll
      for (int r = 0; r < 4; ++r) {
        float s1 = 0.f, s2 = 0.f;
#pragma unroll
        for (int nt = 0; nt < 8; ++nt) {
          float v = acc2[mip][nt][r] + b2v[nt];
          acc2[mip][nt][r] = v;
          s1 += v; s2 += v * v;
        }
#pragma unroll
        for (int m = 1; m < 16; m <<= 1) {
          s1 += __shfl_xor(s1, m, 64);
          s2 += __shfl_xor(s2, m, 64);
        }
        float mu  = s1 * (1.0f / 128.0f);
        float var = s2 * (1.0f / 128.0f) - mu * mu;
        float rs  = rsqrtf(var + 1e-5f);
        int blkrow = w * 64 + (2 * h + mip) * 16 + q * 4 + r;
        long long eg = e0 + blkrow;
        bool valid = eg < E;
        int rv = 0;
        if (MODE == 0 && valid) rv = ridx[eg];
#pragma unroll
        for (int nt = 0; nt < 8; ++nt) {
          int col = nt * 16 + c;
          float y = (acc2[mip][nt][r] - mu) * rs * gv[nt] + bev[nt];
          if (valid) {
            size_t o = (size_t)eg * HDIM + col;
            outp[o] = residf[o] + y;
            if (MODE == 0) atomicAdd(&aggp[(size_t)rv * HDIM + col], y);
          }
        }
      }
    }
  }
}

extern "C" void kernel_launch(void* const* d_in, const int* in_sizes, int n_in,
                              void* d_out, int out_size, void* d_ws, size_t ws_size,
                              hipStream_t stream) {
  (void)n_in; (void)out_size; (void)ws_size;
  const float* x  = (const float*)d_in[0];
  const float* ea = (const float*)d_in[1];
  const float* ew = (const float*)d_in[2];
  const float* P[18];
  for (int i = 0; i < 18; ++i) P[i] = (const float*)d_in[3 + i];
  const int* ei  = (const int*)d_in[21];
  const int* ewi = (const int*)d_in[22];
  const int N  = in_sizes[0] / 128;
  const int EM = in_sizes[21] / 2;
  const int EW = in_sizes[22] / 2;

  char* ws = (char*)d_ws;
  float* aggm = (float*)ws;
  float* aggw = (float*)(ws + (size_t)N * 128 * 4);
  unsigned short* xb  = (unsigned short*)(ws + (size_t)N * 128 * 8);
  unsigned short* bts = (unsigned short*)(ws + (size_t)N * 128 * 8 + (size_t)N * 128 * 2);

  hipMemsetAsync(ws, 0, (size_t)N * 128 * 8, stream);   // zero agg_m, agg_w

  int Nx = N * 64;
  int total = Nx + 3 * 65536;
  prep_kernel<<<(total + 255) / 256, 256, 0, stream>>>(
      x, P[0], P[2], P[6], P[8], P[12], P[14], xb, bts, Nx);

  float* out0 = (float*)d_out;
  float* out1 = out0 + (size_t)N * 128;
  float* out2 = out1 + (size_t)EM * 128;

  unsigned short* Bt1_emb = bts;
  unsigned short* Bt2_emb = bts + 49152;
  unsigned short* Bt1_ewb = bts + 65536;
  unsigned short* Bt2_ewb = bts + 65536 + 49152;
  unsigned short* Bt1_nb  = bts + 131072;
  unsigned short* Bt2_nb  = bts + 131072 + 49152;

  mlp_ln_kernel<0><<<(EM + BM - 1) / BM, 256, 0, stream>>>(
      xb, nullptr, ea, ea, ei, ei + EM,
      Bt1_emb, Bt2_emb, P[1], P[3], P[4], P[5], out1, aggm, EM);
  mlp_ln_kernel<0><<<(EW + BM - 1) / BM, 256, 0, stream>>>(
      xb, nullptr, ew, ew, ewi, ewi + EW,
      Bt1_ewb, Bt2_ewb, P[7], P[9], P[10], P[11], out2, aggw, EW);
  mlp_ln_kernel<1><<<(N + BM - 1) / BM, 256, 0, stream>>>(
      xb, aggm, aggw, x, nullptr, nullptr,
      Bt1_nb, Bt2_nb, P[13], P[15], P[16], P[17], out0, nullptr, N);
}